// Round 3
// baseline (2275.669 us; speedup 1.0000x reference)
//
#include <hip/hip_runtime.h>

// Problem: B*T=3200 seqs, V=25, D=128, N_Q=4, N_E=1024. NROWS=80000.
// d_out: zq [10,240,000] | loss [1] | indices [320,000]
// d_ws needs >= 84.5 MB (21,105,792 floats).
#define ZQ_N    10240000
#define IDX_OFF 10240001
#define FLT_BIG 3.402823466e38f

__device__ __forceinline__ float getc(const float4& v, int k) {
    return k == 0 ? v.x : k == 1 ? v.y : k == 2 ? v.z : v.w;
}

__global__ __launch_bounds__(256) void k_init(float* loss_part) {
    int i = blockIdx.x * 256 + threadIdx.x;
    if (i < 1024) loss_part[i] = 0.f;
}

// wsq[q*1024+j] = ||emb[q][j]||^2
__global__ __launch_bounds__(256) void k_wsq(const float* __restrict__ emb,
                                             float* __restrict__ wsq) {
    int t = threadIdx.x;
    int row = blockIdx.x * 64 + (t >> 2);
    int seg = t & 3;
    const float4* p = (const float4*)(emb + row * 128 + seg * 32);
    float a = 0.f;
#pragma unroll
    for (int i = 0; i < 8; i++) {
        float4 w = p[i];
        a = fmaf(w.x, w.x, a); a = fmaf(w.y, w.y, a);
        a = fmaf(w.z, w.z, a); a = fmaf(w.w, w.w, a);
    }
    a += __shfl_xor(a, 1);
    a += __shfl_xor(a, 2);
    if (seg == 0) wsq[row] = a;
}

// dst[C][R] = src[R][C]^T, R,C multiples of 32. 256 threads, 32x32 LDS tile.
__global__ __launch_bounds__(256) void k_transpose(const float* __restrict__ src,
                                                   float* __restrict__ dst,
                                                   int R, int C) {
    __shared__ float t[32][33];
    const int tx = threadIdx.x & 31, ty = threadIdx.x >> 5;
    const int r0 = blockIdx.y * 32, c0 = blockIdx.x * 32;
#pragma unroll
    for (int i = 0; i < 4; i++)
        t[ty + 8 * i][tx] = src[(size_t)(r0 + ty + 8 * i) * C + c0 + tx];
    __syncthreads();
#pragma unroll
    for (int i = 0; i < 4; i++)
        dst[(size_t)(c0 + ty + 8 * i) * R + r0 + tx] = t[tx][ty + 8 * i];
}

// One block per sequence: ring-GCN + linear(gwT, coalesced, prefetched) + LReLU + LN + res add.
__global__ __launch_bounds__(256) void k_refine(const float* __restrict__ src,
        float* __restrict__ refined, float* __restrict__ s_out,
        const float* __restrict__ An, const float* __restrict__ gwT,
        const float* __restrict__ gb, const float* __restrict__ lsc,
        const float* __restrict__ lbi) {
    __shared__ __align__(16) float Rn[25 * 128];
    __shared__ __align__(16) float nei[32 * 132];   // rows 25..31 junk, discarded
    __shared__ float Al[625];
    const int tid = threadIdx.x;
    const int n = blockIdx.x;

    const float4* sp = (const float4*)(src + n * 3200);
    float4* Rn4 = (float4*)Rn;
    for (int i = tid; i < 800; i += 256) Rn4[i] = sp[i];
    for (int i = tid; i < 625; i += 256) Al[i] = An[i];
    __syncthreads();

    for (int i = tid; i < 3200; i += 256) {
        int v = i >> 7, d = i & 127;
        int vm = (v == 0) ? 24 : v - 1;
        int vp = (v == 24) ? 0 : v + 1;
        float val = Al[v * 25 + vm] * Rn[vm * 128 + d];
        val = fmaf(Al[v * 25 + v],  Rn[v  * 128 + d], val);
        val = fmaf(Al[v * 25 + vp], Rn[vp * 128 + d], val);
        nei[v * 132 + d] = val;
    }
    __syncthreads();

    const int dpg = tid & 31;     // 32 col-groups of 4 dp
    const int vs  = tid >> 5;     // rows vs, vs+8, vs+16, vs+24
    const int dp0 = dpg * 4;

    float acc[4][4];
#pragma unroll
    for (int a = 0; a < 4; a++)
#pragma unroll
        for (int b = 0; b < 4; b++) acc[a][b] = 0.f;

    float4 wc[4];
#pragma unroll
    for (int kk = 0; kk < 4; kk++)
        wc[kk] = *(const float4*)(gwT + kk * 128 + dp0);

#pragma unroll 2
    for (int kg = 0; kg < 128; kg += 4) {
        const int kn = (kg < 124) ? (kg + 4) : kg;   // dummy reload at end
        float4 wn[4];
#pragma unroll
        for (int kk = 0; kk < 4; kk++)
            wn[kk] = *(const float4*)(gwT + (kn + kk) * 128 + dp0);
        float4 xv[4];
#pragma unroll
        for (int i = 0; i < 4; i++)
            xv[i] = *(const float4*)(&nei[(vs + 8 * i) * 132 + kg]);
#pragma unroll
        for (int kk = 0; kk < 4; kk++) {
            float4 w = wc[kk];
#pragma unroll
            for (int i = 0; i < 4; i++) {
                float xs = getc(xv[i], kk);
                acc[i][0] = fmaf(xs, w.x, acc[i][0]);
                acc[i][1] = fmaf(xs, w.y, acc[i][1]);
                acc[i][2] = fmaf(xs, w.z, acc[i][2]);
                acc[i][3] = fmaf(xs, w.w, acc[i][3]);
            }
        }
#pragma unroll
        for (int kk = 0; kk < 4; kk++) wc[kk] = wn[kk];
    }

    float4 b4  = *(const float4*)(gb + dp0);
    float4 sc4 = *(const float4*)(lsc + dp0);
    float4 bi4 = *(const float4*)(lbi + dp0);
    const float bb[4] = {b4.x, b4.y, b4.z, b4.w};
    const float sc[4] = {sc4.x, sc4.y, sc4.z, sc4.w};
    const float bi[4] = {bi4.x, bi4.y, bi4.z, bi4.w};

#pragma unroll
    for (int i = 0; i < 4; i++) {
        int v = vs + 8 * i;
        if (v >= 25) break;       // uniform within each 32-lane group
        float y[4];
#pragma unroll
        for (int c = 0; c < 4; c++) {
            float t = acc[i][c] + bb[c];
            y[c] = (t >= 0.f) ? t : 0.2f * t;       // LeakyReLU(0.2)
        }
        float s1 = y[0] + y[1] + y[2] + y[3];
#pragma unroll
        for (int m = 1; m <= 16; m <<= 1) s1 += __shfl_xor(s1, m);
        float mu = s1 * (1.f / 128.f);
        float d2 = 0.f;
#pragma unroll
        for (int c = 0; c < 4; c++) { float t = y[c] - mu; d2 = fmaf(t, t, d2); }
#pragma unroll
        for (int m = 1; m <= 16; m <<= 1) d2 += __shfl_xor(d2, m);
        float inv = 1.f / sqrtf(d2 * (1.f / 128.f) + 1e-5f);

        float4 rn4 = *(const float4*)(&Rn[v * 128 + dp0]);
        const float rn[4] = {rn4.x, rn4.y, rn4.z, rn4.w};
        float o[4];
#pragma unroll
        for (int c = 0; c < 4; c++)
            o[c] = rn[c] + 0.1f * ((y[c] - mu) * inv * sc[c] + bi[c]);

        *(float4*)(refined + (n * 25 + v) * 128 + dp0) =
            make_float4(o[0], o[1], o[2], o[3]);

        float ss = 0.f;
#pragma unroll
        for (int c = 0; c < 4; c++) ss = fmaf(o[c], o[c], ss);
#pragma unroll
        for (int m = 1; m <= 16; m <<= 1) ss += __shfl_xor(ss, m);
        if (dpg == 0) s_out[n * 25 + v] = ss;
    }
}

// Distance GEMM (X-LDS x prefetched global wT) + exact argmin + update. 64 rows/block.
__global__ __launch_bounds__(256) void k_vq(const float* __restrict__ refined,
        const float* __restrict__ wT,      // [128][4096] k-major, all 4 stages
        const float* __restrict__ emb_k,   // original [1024][128] for gather
        const float* __restrict__ wsq_k, const float* __restrict__ s_g,
        const float* res_src, float* res_dst, float* zq,
        float* __restrict__ idx_out, float* __restrict__ loss_part, int stage) {
    __shared__ __align__(16) float xl[64 * 132];    // 33792 B; reduction aliased below
    __shared__ int il[64];
    float* redv = xl;                 // [16][64], valid only after main loop
    int*   redi = (int*)(xl + 1024);  // [16][64]
    const int tid = threadIdx.x;
    const int row0 = blockIdx.x * 64;
    const int rg = tid & 15;       // rows rg, rg+16, rg+32, rg+48
    const int cg = tid >> 4;       // 16 col-groups

    for (int q = tid; q < 2048; q += 256) {
        int r = q >> 5, kq = (q & 31) * 4;
        *(float4*)(&xl[r * 132 + kq]) = *(const float4*)(refined + (row0 + r) * 128 + kq);
    }
    __syncthreads();

    float sv[4];
#pragma unroll
    for (int rr = 0; rr < 4; rr++) sv[rr] = s_g[row0 + rg + 16 * rr];

    float bestv[4] = {FLT_BIG, FLT_BIG, FLT_BIG, FLT_BIG};
    int   besti[4] = {0, 0, 0, 0};

    const float* wbase = wT + stage * 1024;
    const int jbase = cg * 4;

    // software-pipeline: cA/cB hold W for current k-group, nA/nB prefetch the next
    float4 cA[4], cB[4];
    {
        const float* p0 = wbase + jbase;
#pragma unroll
        for (int kk = 0; kk < 4; kk++) {
            cA[kk] = *(const float4*)(p0 + kk * 4096);
            cB[kk] = *(const float4*)(p0 + kk * 4096 + 64);
        }
    }

    for (int cb = 0; cb < 8; cb++) {
        const int jA = cb * 128 + jbase;
        const int jB = jA + 64;
        const float* wp = wbase + jA;
        float acc[4][8];
#pragma unroll
        for (int a = 0; a < 4; a++)
#pragma unroll
            for (int b = 0; b < 8; b++) acc[a][b] = 0.f;

#pragma unroll 2
        for (int kg = 0; kg < 128; kg += 4) {
            const float* wnext = (kg < 124) ? (wp + (kg + 4) * 4096)
                               : ((cb < 7) ? (wp + 128)          // next cb, kg=0
                                           : (wp + kg * 4096));  // dummy reload
            float4 nA[4], nB[4];
#pragma unroll
            for (int kk = 0; kk < 4; kk++) {
                nA[kk] = *(const float4*)(wnext + kk * 4096);
                nB[kk] = *(const float4*)(wnext + kk * 4096 + 64);
            }

            float4 xv0 = *(const float4*)(&xl[(rg     ) * 132 + kg]);
            float4 xv1 = *(const float4*)(&xl[(rg + 16) * 132 + kg]);
            float4 xv2 = *(const float4*)(&xl[(rg + 32) * 132 + kg]);
            float4 xv3 = *(const float4*)(&xl[(rg + 48) * 132 + kg]);

#pragma unroll
            for (int kk = 0; kk < 4; kk++) {
                float4 wA = cA[kk], wB = cB[kk];
                float x0 = getc(xv0, kk), x1 = getc(xv1, kk);
                float x2 = getc(xv2, kk), x3 = getc(xv3, kk);
                acc[0][0] = fmaf(x0, wA.x, acc[0][0]);
                acc[0][1] = fmaf(x0, wA.y, acc[0][1]);
                acc[0][2] = fmaf(x0, wA.z, acc[0][2]);
                acc[0][3] = fmaf(x0, wA.w, acc[0][3]);
                acc[0][4] = fmaf(x0, wB.x, acc[0][4]);
                acc[0][5] = fmaf(x0, wB.y, acc[0][5]);
                acc[0][6] = fmaf(x0, wB.z, acc[0][6]);
                acc[0][7] = fmaf(x0, wB.w, acc[0][7]);
                acc[1][0] = fmaf(x1, wA.x, acc[1][0]);
                acc[1][1] = fmaf(x1, wA.y, acc[1][1]);
                acc[1][2] = fmaf(x1, wA.z, acc[1][2]);
                acc[1][3] = fmaf(x1, wA.w, acc[1][3]);
                acc[1][4] = fmaf(x1, wB.x, acc[1][4]);
                acc[1][5] = fmaf(x1, wB.y, acc[1][5]);
                acc[1][6] = fmaf(x1, wB.z, acc[1][6]);
                acc[1][7] = fmaf(x1, wB.w, acc[1][7]);
                acc[2][0] = fmaf(x2, wA.x, acc[2][0]);
                acc[2][1] = fmaf(x2, wA.y, acc[2][1]);
                acc[2][2] = fmaf(x2, wA.z, acc[2][2]);
                acc[2][3] = fmaf(x2, wA.w, acc[2][3]);
                acc[2][4] = fmaf(x2, wB.x, acc[2][4]);
                acc[2][5] = fmaf(x2, wB.y, acc[2][5]);
                acc[2][6] = fmaf(x2, wB.z, acc[2][6]);
                acc[2][7] = fmaf(x2, wB.w, acc[2][7]);
                acc[3][0] = fmaf(x3, wA.x, acc[3][0]);
                acc[3][1] = fmaf(x3, wA.y, acc[3][1]);
                acc[3][2] = fmaf(x3, wA.z, acc[3][2]);
                acc[3][3] = fmaf(x3, wA.w, acc[3][3]);
                acc[3][4] = fmaf(x3, wB.x, acc[3][4]);
                acc[3][5] = fmaf(x3, wB.y, acc[3][5]);
                acc[3][6] = fmaf(x3, wB.z, acc[3][6]);
                acc[3][7] = fmaf(x3, wB.w, acc[3][7]);
            }
#pragma unroll
            for (int kk = 0; kk < 4; kk++) { cA[kk] = nA[kk]; cB[kk] = nB[kk]; }
        }

#pragma unroll
        for (int c = 0; c < 4; c++) {
            float wqA = wsq_k[jA + c];
            float wqB = wsq_k[jB + c];
#pragma unroll
            for (int rr = 0; rr < 4; rr++) {
                float dA = (sv[rr] - 2.0f * acc[rr][c]) + wqA;
                if (dA < bestv[rr] || (dA == bestv[rr] && jA + c < besti[rr])) {
                    bestv[rr] = dA; besti[rr] = jA + c;
                }
                float dB = (sv[rr] - 2.0f * acc[rr][c + 4]) + wqB;
                if (dB < bestv[rr] || (dB == bestv[rr] && jB + c < besti[rr])) {
                    bestv[rr] = dB; besti[rr] = jB + c;
                }
            }
        }
    }

    __syncthreads();   // xl reads done; safe to alias reduction buffers
#pragma unroll
    for (int rr = 0; rr < 4; rr++) {
        redv[cg * 64 + rg + 16 * rr] = bestv[rr];
        redi[cg * 64 + rg + 16 * rr] = besti[rr];
    }
    __syncthreads();
    if (tid < 64) {
        float bv = redv[tid]; int bi = redi[tid];
#pragma unroll
        for (int c = 1; c < 16; c++) {
            float v = redv[c * 64 + tid]; int i2 = redi[c * 64 + tid];
            if (v < bv || (v == bv && i2 < bi)) { bv = v; bi = i2; }
        }
        il[tid] = bi;
        idx_out[(row0 + tid) * 4 + stage] = (float)bi;
    }
    __syncthreads();

    // update: q = W[idx]; loss += ||q - res||^2; res -= q; cum += q
    const int r = tid >> 2, seg = tid & 3;
    const int row = row0 + r;
    const int idx = il[r];
    const float4* qp = (const float4*)(emb_k + idx * 128 + seg * 32);
    const float4* rp = (const float4*)(res_src + row * 128 + seg * 32);
    float4* rw = (float4*)(res_dst + row * 128 + seg * 32);
    float4* zp = (float4*)(zq + row * 128 + seg * 32);
    float acc = 0.f;
#pragma unroll
    for (int i = 0; i < 8; i++) {
        float4 q4 = qp[i];
        float4 r4 = rp[i];
        float dx = q4.x - r4.x, dy = q4.y - r4.y, dz = q4.z - r4.z, dw = q4.w - r4.w;
        acc = fmaf(dx, dx, acc); acc = fmaf(dy, dy, acc);
        acc = fmaf(dz, dz, acc); acc = fmaf(dw, dw, acc);
        rw[i] = make_float4(r4.x - q4.x, r4.y - q4.y, r4.z - q4.z, r4.w - q4.w);
        if (stage == 0) {
            zp[i] = q4;
        } else {
            float4 z4 = zp[i];
            zp[i] = make_float4(z4.x + q4.x, z4.y + q4.y, z4.z + q4.z, z4.w + q4.w);
        }
    }
    acc += __shfl_xor(acc, 1);  acc += __shfl_xor(acc, 2);
    acc += __shfl_xor(acc, 4);  acc += __shfl_xor(acc, 8);
    acc += __shfl_xor(acc, 16); acc += __shfl_xor(acc, 32);
    if ((tid & 63) == 0) atomicAdd(&loss_part[blockIdx.x & 1023], acc);
}

__global__ __launch_bounds__(256) void k_loss(const float* __restrict__ loss_part,
                                              float* __restrict__ out) {
    int t = threadIdx.x;
    float a = loss_part[t] + loss_part[t + 256] + loss_part[t + 512] + loss_part[t + 768];
#pragma unroll
    for (int m = 1; m <= 32; m <<= 1) a += __shfl_xor(a, m);
    __shared__ float w[4];
    if ((t & 63) == 0) w[t >> 6] = a;
    __syncthreads();
    if (t == 0) {
        float s = w[0] + w[1] + w[2] + w[3];
        out[ZQ_N] = s * (1.25f / (128.f * 320000.f));
    }
}

extern "C" void kernel_launch(void* const* d_in, const int* in_sizes, int n_in,
                              void* d_out, int out_size, void* d_ws, size_t ws_size,
                              hipStream_t stream) {
    (void)in_sizes; (void)n_in; (void)out_size; (void)ws_size;
    const float* z   = (const float*)d_in[0];
    const float* emb = (const float*)d_in[1];
    const float* An  = (const float*)d_in[2];
    const float* gw  = (const float*)d_in[3];
    const float* gb  = (const float*)d_in[4];
    const float* lsc = (const float*)d_in[5];
    const float* lbi = (const float*)d_in[6];

    float* out     = (float*)d_out;
    float* zq      = out;
    float* idx_out = out + IDX_OFF;

    float* ws        = (float*)d_ws;
    float* resbuf    = ws;                   // 10,240,000
    float* refined   = ws + 10240000;        // 10,240,000
    float* wT        = ws + 20480000;        // 524,288  [128][4096]
    float* gwT       = ws + 21004288;        // 16,384   [128][128]
    float* s_g       = ws + 21020672;        // 80,000
    float* wsq       = ws + 21100672;        // 4,096
    float* loss_part = ws + 21104768;        // 1,024   (end: 21,105,792 floats)

    k_init<<<4, 256, 0, stream>>>(loss_part);
    k_wsq<<<64, 256, 0, stream>>>(emb, wsq);
    k_transpose<<<dim3(4, 128), 256, 0, stream>>>(emb, wT, 4096, 128);
    k_transpose<<<dim3(4, 4), 256, 0, stream>>>(gw, gwT, 128, 128);
    for (int k = 0; k < 4; k++) {
        const float* src = (k == 0) ? z : resbuf;
        k_refine<<<3200, 256, 0, stream>>>(src, refined, s_g, An, gwT, gb, lsc, lbi);
        k_vq<<<1250, 256, 0, stream>>>(refined, wT, emb + k * 131072, wsq + k * 1024,
                                       s_g, src, resbuf, zq, idx_out, loss_part, k);
    }
    k_loss<<<1, 256, 0, stream>>>(loss_part, out);
}

// Round 4
// 1425.568 us; speedup vs baseline: 1.5963x; 1.5963x over previous
//
#include <hip/hip_runtime.h>

// Problem: B*T=3200 seqs, V=25, D=128, N_Q=4, N_E=1024. NROWS=80000.
// d_out: zq [10,240,000] | loss [1] | indices [320,000]
#define ZQ_N    10240000
#define IDX_OFF 10240001
#define FLT_BIG 3.402823466e38f

typedef __bf16 bf16x8 __attribute__((ext_vector_type(8)));
typedef float  f32x4  __attribute__((ext_vector_type(4)));

__device__ __forceinline__ float getc(const float4& v, int k) {
    return k == 0 ? v.x : k == 1 ? v.y : k == 2 ? v.z : v.w;
}

// round-to-nearest-even fp32 -> bf16 (bit pattern), and back
__device__ __forceinline__ unsigned short f2bf(float f) {
    unsigned int u = __float_as_uint(f);
    unsigned int r = u + 0x7FFFu + ((u >> 16) & 1u);
    return (unsigned short)(r >> 16);
}
__device__ __forceinline__ float bf2f(unsigned short h) {
    return __uint_as_float(((unsigned int)h) << 16);
}

__global__ __launch_bounds__(256) void k_init(float* loss_part) {
    int i = blockIdx.x * 256 + threadIdx.x;
    if (i < 1024) loss_part[i] = 0.f;
}

// wsq[q*1024+j] = ||emb[q][j]||^2
__global__ __launch_bounds__(256) void k_wsq(const float* __restrict__ emb,
                                             float* __restrict__ wsq) {
    int t = threadIdx.x;
    int row = blockIdx.x * 64 + (t >> 2);
    int seg = t & 3;
    const float4* p = (const float4*)(emb + row * 128 + seg * 32);
    float a = 0.f;
#pragma unroll
    for (int i = 0; i < 8; i++) {
        float4 w = p[i];
        a = fmaf(w.x, w.x, a); a = fmaf(w.y, w.y, a);
        a = fmaf(w.z, w.z, a); a = fmaf(w.w, w.w, a);
    }
    a += __shfl_xor(a, 1);
    a += __shfl_xor(a, 2);
    if (seg == 0) wsq[row] = a;
}

// split emb (4*1024*128 fp32) into bf16x3: w ~= wh + wm + wl
__global__ __launch_bounds__(256) void k_wsplit(const float* __restrict__ emb,
        unsigned short* __restrict__ wh, unsigned short* __restrict__ wm,
        unsigned short* __restrict__ wl) {
    int i = blockIdx.x * 256 + threadIdx.x;   // 524288 total
    float v = emb[i];
    unsigned short h = f2bf(v); float fh = bf2f(h);
    float r1 = v - fh;                        // exact (Sterbenz)
    unsigned short m = f2bf(r1); float fm = bf2f(m);
    float r2 = r1 - fm;                       // exact
    wh[i] = h; wm[i] = m; wl[i] = f2bf(r2);
}

// dst[C][R] = src[R][C]^T, R,C multiples of 32.
__global__ __launch_bounds__(256) void k_transpose(const float* __restrict__ src,
                                                   float* __restrict__ dst,
                                                   int R, int C) {
    __shared__ float t[32][33];
    const int tx = threadIdx.x & 31, ty = threadIdx.x >> 5;
    const int r0 = blockIdx.y * 32, c0 = blockIdx.x * 32;
#pragma unroll
    for (int i = 0; i < 4; i++)
        t[ty + 8 * i][tx] = src[(size_t)(r0 + ty + 8 * i) * C + c0 + tx];
    __syncthreads();
#pragma unroll
    for (int i = 0; i < 4; i++)
        dst[(size_t)(c0 + ty + 8 * i) * R + r0 + tx] = t[tx][ty + 8 * i];
}

// One block per sequence: ring-GCN + linear(gwT) + LeakyReLU + LN + res add. (R2 verbatim)
__global__ __launch_bounds__(256) void k_refine(const float* __restrict__ src,
        float* __restrict__ refined, float* __restrict__ s_out,
        const float* __restrict__ An, const float* __restrict__ gwT,
        const float* __restrict__ gb, const float* __restrict__ lsc,
        const float* __restrict__ lbi) {
    __shared__ __align__(16) float Rn[25 * 128];
    __shared__ __align__(16) float nei[32 * 132];
    __shared__ float Al[625];
    const int tid = threadIdx.x;
    const int n = blockIdx.x;

    const float4* sp = (const float4*)(src + n * 3200);
    float4* Rn4 = (float4*)Rn;
    for (int i = tid; i < 800; i += 256) Rn4[i] = sp[i];
    for (int i = tid; i < 625; i += 256) Al[i] = An[i];
    __syncthreads();

    for (int i = tid; i < 3200; i += 256) {
        int v = i >> 7, d = i & 127;
        int vm = (v == 0) ? 24 : v - 1;
        int vp = (v == 24) ? 0 : v + 1;
        float val = Al[v * 25 + vm] * Rn[vm * 128 + d];
        val = fmaf(Al[v * 25 + v],  Rn[v  * 128 + d], val);
        val = fmaf(Al[v * 25 + vp], Rn[vp * 128 + d], val);
        nei[v * 132 + d] = val;
    }
    __syncthreads();

    const int dpg = tid & 31;
    const int vs  = tid >> 5;
    const int dp0 = dpg * 4;

    float acc[4][4];
#pragma unroll
    for (int a = 0; a < 4; a++)
#pragma unroll
        for (int b = 0; b < 4; b++) acc[a][b] = 0.f;

    for (int kg = 0; kg < 128; kg += 4) {
        float4 xv[4];
#pragma unroll
        for (int i = 0; i < 4; i++)
            xv[i] = *(const float4*)(&nei[(vs + 8 * i) * 132 + kg]);
#pragma unroll
        for (int kk = 0; kk < 4; kk++) {
            float4 w = *(const float4*)(gwT + (kg + kk) * 128 + dp0);
#pragma unroll
            for (int i = 0; i < 4; i++) {
                float xs = getc(xv[i], kk);
                acc[i][0] = fmaf(xs, w.x, acc[i][0]);
                acc[i][1] = fmaf(xs, w.y, acc[i][1]);
                acc[i][2] = fmaf(xs, w.z, acc[i][2]);
                acc[i][3] = fmaf(xs, w.w, acc[i][3]);
            }
        }
    }

    float4 b4  = *(const float4*)(gb + dp0);
    float4 sc4 = *(const float4*)(lsc + dp0);
    float4 bi4 = *(const float4*)(lbi + dp0);
    const float bb[4] = {b4.x, b4.y, b4.z, b4.w};
    const float sc[4] = {sc4.x, sc4.y, sc4.z, sc4.w};
    const float bi[4] = {bi4.x, bi4.y, bi4.z, bi4.w};

#pragma unroll
    for (int i = 0; i < 4; i++) {
        int v = vs + 8 * i;
        if (v >= 25) break;
        float y[4];
#pragma unroll
        for (int c = 0; c < 4; c++) {
            float t = acc[i][c] + bb[c];
            y[c] = (t >= 0.f) ? t : 0.2f * t;
        }
        float s1 = y[0] + y[1] + y[2] + y[3];
#pragma unroll
        for (int m = 1; m <= 16; m <<= 1) s1 += __shfl_xor(s1, m);
        float mu = s1 * (1.f / 128.f);
        float d2 = 0.f;
#pragma unroll
        for (int c = 0; c < 4; c++) { float t = y[c] - mu; d2 = fmaf(t, t, d2); }
#pragma unroll
        for (int m = 1; m <= 16; m <<= 1) d2 += __shfl_xor(d2, m);
        float inv = 1.f / sqrtf(d2 * (1.f / 128.f) + 1e-5f);

        float4 rn4 = *(const float4*)(&Rn[v * 128 + dp0]);
        const float rn[4] = {rn4.x, rn4.y, rn4.z, rn4.w};
        float o[4];
#pragma unroll
        for (int c = 0; c < 4; c++)
            o[c] = rn[c] + 0.1f * ((y[c] - mu) * inv * sc[c] + bi[c]);

        *(float4*)(refined + (n * 25 + v) * 128 + dp0) =
            make_float4(o[0], o[1], o[2], o[3]);

        float ss = 0.f;
#pragma unroll
        for (int c = 0; c < 4; c++) ss = fmaf(o[c], o[c], ss);
#pragma unroll
        for (int m = 1; m <= 16; m <<= 1) ss += __shfl_xor(ss, m);
        if (dpg == 0) s_out[n * 25 + v] = ss;
    }
}

// MFMA distance GEMM via bf16x3 split + exact argmin + update. 64 rows/block, 4 waves.
__global__ __launch_bounds__(256) void k_vq(const float* __restrict__ refined,
        const unsigned short* __restrict__ wh,   // [1024][128] bf16, this stage
        const unsigned short* __restrict__ wm,
        const unsigned short* __restrict__ wl,
        const float* __restrict__ emb_k, const float* __restrict__ wsq_k,
        const float* __restrict__ s_g,
        const float* res_src, float* res_dst, float* zq,
        float* __restrict__ idx_out, float* __restrict__ loss_part, int stage) {
    __shared__ __align__(16) unsigned short xh_s[64 * 136];  // row stride 136 (pad 8)
    __shared__ __align__(16) unsigned short xm_s[64 * 136];
    __shared__ __align__(16) unsigned short xl_s[64 * 136];
    __shared__ int il[64];
    const int tid = threadIdx.x;
    const int row0 = blockIdx.x * 64;

    // stage X tile: fp32 -> bf16x3 split into LDS
    for (int i = tid; i < 1024; i += 256) {       // 8-elem chunks
        int r = i >> 4, k8 = (i & 15) * 8;
        const float* srcp = refined + (row0 + r) * 128 + k8;
        float4 a = *(const float4*)(srcp);
        float4 b = *(const float4*)(srcp + 4);
        float vv[8] = {a.x, a.y, a.z, a.w, b.x, b.y, b.z, b.w};
        union { unsigned short us[8]; uint4 u4; } ph, pm, pl;
#pragma unroll
        for (int j = 0; j < 8; j++) {
            unsigned short h = f2bf(vv[j]); float fh = bf2f(h);
            float r1 = vv[j] - fh;
            unsigned short m = f2bf(r1); float fm = bf2f(m);
            float r2 = r1 - fm;
            ph.us[j] = h; pm.us[j] = m; pl.us[j] = f2bf(r2);
        }
        int off = r * 136 + k8;
        *(uint4*)(&xh_s[off]) = ph.u4;
        *(uint4*)(&xm_s[off]) = pm.u4;
        *(uint4*)(&xl_s[off]) = pl.u4;
    }
    __syncthreads();

    const int lane = tid & 63;
    const int w    = tid >> 6;       // wave id: cols w*64 within each 256-panel
    const int quad = lane >> 4;
    const int lm   = lane & 15;

    // s_row: ||x||^2 for the 16 rows this lane's C-frags cover
    float sr[16];
#pragma unroll
    for (int rt = 0; rt < 4; rt++) {
        float4 t = *(const float4*)(s_g + row0 + rt * 16 + quad * 4);
        sr[rt * 4 + 0] = t.x; sr[rt * 4 + 1] = t.y;
        sr[rt * 4 + 2] = t.z; sr[rt * 4 + 3] = t.w;
    }

    float bestv[16];
    int   besti[16];
#pragma unroll
    for (int s = 0; s < 16; s++) { bestv[s] = FLT_BIG; besti[s] = 0; }

    for (int p = 0; p < 4; p++) {
        const int c0p = p * 256 + w * 64;
        f32x4 acc[4][4];                         // [ct][rt]
#pragma unroll
        for (int a = 0; a < 4; a++)
#pragma unroll
            for (int b = 0; b < 4; b++) acc[a][b] = (f32x4){0.f, 0.f, 0.f, 0.f};

#pragma unroll
        for (int k0 = 0; k0 < 128; k0 += 32) {
            const int ko = k0 + quad * 8;
            bf16x8 ah[4], am[4], al[4];
#pragma unroll
            for (int rt = 0; rt < 4; rt++) {
                int off = (rt * 16 + lm) * 136 + ko;
                ah[rt] = *(const bf16x8*)(&xh_s[off]);
                am[rt] = *(const bf16x8*)(&xm_s[off]);
                al[rt] = *(const bf16x8*)(&xl_s[off]);
            }
#pragma unroll
            for (int ct = 0; ct < 4; ct++) {
                const int woff = (c0p + ct * 16 + lm) * 128 + ko;
                bf16x8 bh = *(const bf16x8*)(wh + woff);
                bf16x8 bm = *(const bf16x8*)(wm + woff);
                bf16x8 bl = *(const bf16x8*)(wl + woff);
#pragma unroll
                for (int rt = 0; rt < 4; rt++)
                    acc[ct][rt] = __builtin_amdgcn_mfma_f32_16x16x32_bf16(ah[rt], bh, acc[ct][rt], 0, 0, 0);
#pragma unroll
                for (int rt = 0; rt < 4; rt++)
                    acc[ct][rt] = __builtin_amdgcn_mfma_f32_16x16x32_bf16(ah[rt], bm, acc[ct][rt], 0, 0, 0);
#pragma unroll
                for (int rt = 0; rt < 4; rt++)
                    acc[ct][rt] = __builtin_amdgcn_mfma_f32_16x16x32_bf16(am[rt], bh, acc[ct][rt], 0, 0, 0);
#pragma unroll
                for (int rt = 0; rt < 4; rt++)
                    acc[ct][rt] = __builtin_amdgcn_mfma_f32_16x16x32_bf16(ah[rt], bl, acc[ct][rt], 0, 0, 0);
#pragma unroll
                for (int rt = 0; rt < 4; rt++)
                    acc[ct][rt] = __builtin_amdgcn_mfma_f32_16x16x32_bf16(al[rt], bh, acc[ct][rt], 0, 0, 0);
#pragma unroll
                for (int rt = 0; rt < 4; rt++)
                    acc[ct][rt] = __builtin_amdgcn_mfma_f32_16x16x32_bf16(am[rt], bm, acc[ct][rt], 0, 0, 0);
            }
        }

        // epilogue: dist = (||x||^2 - 2 x.w) + ||w||^2 ; running argmin (cols ascending)
#pragma unroll
        for (int ct = 0; ct < 4; ct++) {
            const int col = c0p + ct * 16 + lm;
            const float wq = wsq_k[col];
#pragma unroll
            for (int rt = 0; rt < 4; rt++) {
#pragma unroll
                for (int reg = 0; reg < 4; reg++) {
                    float d = (sr[rt * 4 + reg] - 2.0f * acc[ct][rt][reg]) + wq;
                    int s = rt * 4 + reg;
                    if (d < bestv[s] || (d == bestv[s] && col < besti[s])) {
                        bestv[s] = d; besti[s] = col;
                    }
                }
            }
        }
    }

    // cross-lane argmin over lm (16 lanes hold same rows, different cols)
#pragma unroll
    for (int s = 0; s < 16; s++) {
#pragma unroll
        for (int m = 1; m <= 8; m <<= 1) {
            float ov = __shfl_xor(bestv[s], m);
            int   oi = __shfl_xor(besti[s], m);
            if (ov < bestv[s] || (ov == bestv[s] && oi < besti[s])) {
                bestv[s] = ov; besti[s] = oi;
            }
        }
    }

    __syncthreads();                 // done reading x LDS; alias reduction buffers
    float* redv = (float*)xh_s;      // [4][64]
    int*   redi = (int*)xm_s;        // [4][64]
    if (lm == 0) {
#pragma unroll
        for (int s = 0; s < 16; s++) {
            int row = (s >> 2) * 16 + quad * 4 + (s & 3);
            redv[w * 64 + row] = bestv[s];
            redi[w * 64 + row] = besti[s];
        }
    }
    __syncthreads();
    if (tid < 64) {
        float bv = redv[tid]; int bi = redi[tid];
#pragma unroll
        for (int ww = 1; ww < 4; ww++) {
            float v2 = redv[ww * 64 + tid]; int i2 = redi[ww * 64 + tid];
            if (v2 < bv || (v2 == bv && i2 < bi)) { bv = v2; bi = i2; }
        }
        il[tid] = bi;
        idx_out[(row0 + tid) * 4 + stage] = (float)bi;
    }
    __syncthreads();

    // update: q = W[idx]; loss += ||q - res||^2; res -= q; cum += q   (R2 verbatim)
    const int r = tid >> 2, seg = tid & 3;
    const int row = row0 + r;
    const int idx = il[r];
    const float4* qp = (const float4*)(emb_k + idx * 128 + seg * 32);
    const float4* rp = (const float4*)(res_src + row * 128 + seg * 32);
    float4* rw = (float4*)(res_dst + row * 128 + seg * 32);
    float4* zp = (float4*)(zq + row * 128 + seg * 32);
    float accl = 0.f;
#pragma unroll
    for (int i = 0; i < 8; i++) {
        float4 q4 = qp[i];
        float4 r4 = rp[i];
        float dx = q4.x - r4.x, dy = q4.y - r4.y, dz = q4.z - r4.z, dw = q4.w - r4.w;
        accl = fmaf(dx, dx, accl); accl = fmaf(dy, dy, accl);
        accl = fmaf(dz, dz, accl); accl = fmaf(dw, dw, accl);
        rw[i] = make_float4(r4.x - q4.x, r4.y - q4.y, r4.z - q4.z, r4.w - q4.w);
        if (stage == 0) {
            zp[i] = q4;
        } else {
            float4 z4 = zp[i];
            zp[i] = make_float4(z4.x + q4.x, z4.y + q4.y, z4.z + q4.z, z4.w + q4.w);
        }
    }
    accl += __shfl_xor(accl, 1);  accl += __shfl_xor(accl, 2);
    accl += __shfl_xor(accl, 4);  accl += __shfl_xor(accl, 8);
    accl += __shfl_xor(accl, 16); accl += __shfl_xor(accl, 32);
    if ((tid & 63) == 0) atomicAdd(&loss_part[blockIdx.x & 1023], accl);
}

__global__ __launch_bounds__(256) void k_loss(const float* __restrict__ loss_part,
                                              float* __restrict__ out) {
    int t = threadIdx.x;
    float a = loss_part[t] + loss_part[t + 256] + loss_part[t + 512] + loss_part[t + 768];
#pragma unroll
    for (int m = 1; m <= 32; m <<= 1) a += __shfl_xor(a, m);
    __shared__ float w[4];
    if ((t & 63) == 0) w[t >> 6] = a;
    __syncthreads();
    if (t == 0) {
        float s = w[0] + w[1] + w[2] + w[3];
        out[ZQ_N] = s * (1.25f / (128.f * 320000.f));
    }
}

extern "C" void kernel_launch(void* const* d_in, const int* in_sizes, int n_in,
                              void* d_out, int out_size, void* d_ws, size_t ws_size,
                              hipStream_t stream) {
    (void)in_sizes; (void)n_in; (void)out_size; (void)ws_size;
    const float* z   = (const float*)d_in[0];
    const float* emb = (const float*)d_in[1];
    const float* An  = (const float*)d_in[2];
    const float* gw  = (const float*)d_in[3];
    const float* gb  = (const float*)d_in[4];
    const float* lsc = (const float*)d_in[5];
    const float* lbi = (const float*)d_in[6];

    float* out     = (float*)d_out;
    float* zq      = out;
    float* idx_out = out + IDX_OFF;

    float* ws        = (float*)d_ws;
    float* resbuf    = ws;                   // 10,240,000
    float* refined   = ws + 10240000;        // 10,240,000
    float* gwT       = ws + 20480000;        // 16,384
    unsigned short* wh_us = (unsigned short*)(ws + 20496384);  // 524,288 us (262,144 f)
    unsigned short* wm_us = (unsigned short*)(ws + 20758528);  // 524,288 us
    unsigned short* wl_us = (unsigned short*)(ws + 21020672);  // 524,288 us
    float* s_g       = ws + 21282816;        // 80,000
    float* wsq       = ws + 21362816;        // 4,096
    float* loss_part = ws + 21366912;        // 1,024  (end: 21,367,936 floats = 85.5 MB)

    k_init<<<4, 256, 0, stream>>>(loss_part);
    k_wsq<<<64, 256, 0, stream>>>(emb, wsq);
    k_wsplit<<<2048, 256, 0, stream>>>(emb, wh_us, wm_us, wl_us);
    k_transpose<<<dim3(4, 4), 256, 0, stream>>>(gw, gwT, 128, 128);
    for (int k = 0; k < 4; k++) {
        const float* src = (k == 0) ? z : resbuf;
        k_refine<<<3200, 256, 0, stream>>>(src, refined, s_g, An, gwT, gb, lsc, lbi);
        k_vq<<<1250, 256, 0, stream>>>(refined,
                                       wh_us + k * 131072, wm_us + k * 131072,
                                       wl_us + k * 131072,
                                       emb + k * 131072, wsq + k * 1024,
                                       s_g, src, resbuf, zq, idx_out, loss_part, k);
    }
    k_loss<<<1, 256, 0, stream>>>(loss_part, out);
}